// Round 5
// baseline (86.531 us; speedup 1.0000x reference)
//
#include <hip/hip_runtime.h>
#include <hip/hip_bf16.h>
#include <hip/hip_cooperative_groups.h>
#include <math.h>

namespace cg = cooperative_groups;

constexpr int Bn = 1024;   // batch
constexpr int Cn = 1000;   // classes
constexpr int Dn = 256;    // feature dim
constexpr float EPS = 1e-4f;

typedef __attribute__((ext_vector_type(8))) short bf16x8;
typedef __attribute__((ext_vector_type(4))) float f32x4;

// f32 -> bf16 round-to-nearest-even
static __device__ __forceinline__ unsigned short f2bf(float x) {
    union { float f; unsigned u; } v; v.f = x;
    return (unsigned short)((v.u + 0x7fffu + ((v.u >> 16) & 1u)) >> 16);
}
static __device__ __forceinline__ float bf2f(unsigned short h) {
    union { unsigned u; float f; } v; v.u = ((unsigned)h) << 16; return v.f;
}

// ---------------------------------------------------------------------------
// Single cooperative kernel, 256 blocks x 256 threads (1 block/CU).
// P0: Gb = bf16([z; mu_clamped])   (rows 0..1023 = z, 1024..2047 = mu)
//     Ftb = bf16(F^T)              (so phase-1 B-frags are k-contiguous)
//     epsn[g] = EPS*||G_row g||^2 (from f32 inputs), lse = logsumexp(logits)
// P1: Wb = bf16(Gb @ F)  (MFMA, 64x32 tiles, no LDS; frags from L2)
// P2: out[b][c] = W_Y(b).W_U(c) + rowbias[b] + colbias[c]  (MFMA 64x64)
//     with rowbias = -0.5*(||Y_b||^2 + epsn), colbias = logit-lse-0.5*(||U_c||^2+epsn)
__global__ __launch_bounds__(256) void lda_fused_kernel(
        const float* __restrict__ z, const float* __restrict__ mu,
        const float* __restrict__ logits, const float* __restrict__ F,
        unsigned short* __restrict__ Gb,   // [2048][256] bf16
        unsigned short* __restrict__ Ftb,  // [256][256] bf16 (= F^T)
        unsigned short* __restrict__ Wb,   // [2048][256] bf16 (= G @ F)
        float* __restrict__ epsn,          // [2048]
        float* __restrict__ lse_p,         // [1]
        float* __restrict__ out) {         // [1024][1000]
    const int bid = blockIdx.x, tid = threadIdx.x;
    __shared__ float red[64][4];
    __shared__ float rowbias[64], colbias[64];
    __shared__ float rl[256];

    // ---------------- phase 0 ----------------
    if (bid < 16) {                       // z -> bf16 (flat, coalesced)
        const size_t b4 = (size_t)bid * 4096;
#pragma unroll
        for (int i = 0; i < 16; ++i) {
            const size_t e4 = b4 + i * 256 + tid;       // float4 index
            const float4 v = ((const float4*)z)[e4];
            ushort4 s;
            s.x = f2bf(v.x); s.y = f2bf(v.y); s.z = f2bf(v.z); s.w = f2bf(v.w);
            ((ushort4*)Gb)[e4] = s;
        }
    } else if (bid < 32) {                // mu -> bf16 rows 1024.., clamped
        const int rb = bid - 16;
        const int r = tid >> 2, q = tid & 3;
        const int gr = rb * 64 + r;                     // 0..1023
        const int rm = gr < Cn ? gr : Cn - 1;
        const float4* src = (const float4*)&mu[(size_t)rm * Dn + q * 64];
        ushort4* dst = (ushort4*)&Gb[(size_t)(1024 + gr) * Dn + q * 64];
#pragma unroll
        for (int i = 0; i < 16; ++i) {
            const float4 v = src[i];
            ushort4 s;
            s.x = f2bf(v.x); s.y = f2bf(v.y); s.z = f2bf(v.z); s.w = f2bf(v.w);
            dst[i] = s;
        }
    } else if (bid < 64) {                // epsn = EPS*||row||^2 from f32 inputs
        const int eb = bid - 32;
        const int r = tid >> 2, q = tid & 3;
        const int g = eb * 64 + r;                      // 0..2047
        const float* src = (g < 1024)
            ? &z[(size_t)g * Dn]
            : &mu[(size_t)((g - 1024) < Cn ? (g - 1024) : Cn - 1) * Dn];
        const float4* p4 = (const float4*)&src[q * 64];
        float s = 0.f;
#pragma unroll
        for (int i = 0; i < 16; ++i) {
            const float4 v = p4[i];
            s += v.x * v.x + v.y * v.y + v.z * v.z + v.w * v.w;
        }
        red[r][q] = s;
        __syncthreads();
        if (tid < 64)
            epsn[eb * 64 + tid] = EPS * (red[tid][0] + red[tid][1] +
                                         red[tid][2] + red[tid][3]);
    } else if (bid == 64) {               // lse = logsumexp(logits)
        float mx = -INFINITY;
        for (int i = tid; i < Cn; i += 256) mx = fmaxf(mx, logits[i]);
        rl[tid] = mx; __syncthreads();
        for (int s = 128; s > 0; s >>= 1) {
            if (tid < s) rl[tid] = fmaxf(rl[tid], rl[tid + s]);
            __syncthreads();
        }
        mx = rl[0]; __syncthreads();
        float sm = 0.f;
        for (int i = tid; i < Cn; i += 256) sm += expf(logits[i] - mx);
        rl[tid] = sm; __syncthreads();
        for (int s = 128; s > 0; s >>= 1) {
            if (tid < s) rl[tid] += rl[tid + s];
            __syncthreads();
        }
        if (tid == 0) *lse_p = mx + logf(rl[0]);
    } else if (bid >= 240) {              // F^T -> bf16 (scalar gather, coalesced write)
        const int fb = bid - 240;
#pragma unroll
        for (int i = 0; i < 16; ++i) {
            const int c = fb * 16 + i;
            Ftb[(size_t)c * Dn + tid] = f2bf(F[(size_t)tid * Dn + c]);
        }
    }

    cg::this_grid().sync();

    // ---------------- phase 1: Wb = Gb @ F (64 rows x 32 cols per block) ----
    {
        const int row0 = (bid >> 3) * 64;     // 32 row-tiles over 2048 rows
        const int col0 = (bid & 7) * 32;      // 8 col-tiles over 256 cols
        const int lane = tid & 63, w = tid >> 6;
        const int wr = (w >> 1) * 32, wc = (w & 1) * 16;
        const int la = lane & 15, kg = lane >> 4;

        const bf16x8* pa = (const bf16x8*)&Gb[(size_t)(row0 + wr + la) * Dn + kg * 8];
        const bf16x8* pb = (const bf16x8*)&Ftb[(size_t)(col0 + wc + la) * Dn + kg * 8];

        f32x4 acc0 = {0.f, 0.f, 0.f, 0.f};
        f32x4 acc1 = {0.f, 0.f, 0.f, 0.f};
#pragma unroll
        for (int kt = 0; kt < 8; ++kt) {
            const bf16x8 b0 = pb[kt * 4];
            const bf16x8 a0 = pa[kt * 4];
            const bf16x8 a1 = pa[kt * 4 + 512];   // +16 rows
            acc0 = __builtin_amdgcn_mfma_f32_16x16x32_bf16(a0, b0, acc0, 0, 0, 0);
            acc1 = __builtin_amdgcn_mfma_f32_16x16x32_bf16(a1, b0, acc1, 0, 0, 0);
        }
        // C/D: col = lane&15, row = kg*4 + j
        const int col = col0 + wc + la;
        const int rb0 = row0 + wr + kg * 4;
#pragma unroll
        for (int j = 0; j < 4; ++j) {
            Wb[(size_t)(rb0 + j) * Dn + col]      = f2bf(acc0[j]);
            Wb[(size_t)(rb0 + 16 + j) * Dn + col] = f2bf(acc1[j]);
        }
    }

    cg::this_grid().sync();

    // ---------------- phase 2: main GEMM + epilogue ----------------
    const int row0 = (bid >> 4) * 64;     // B rows
    const int col0 = (bid & 15) * 64;     // C cols
    const int r = tid >> 2, q = tid & 3;

    {   // Y row norms
        const bf16x8* py = (const bf16x8*)&Wb[(size_t)(row0 + r) * Dn + q * 64];
        float s = 0.f;
#pragma unroll
        for (int i = 0; i < 8; ++i) {
            const bf16x8 h = py[i];
#pragma unroll
            for (int j = 0; j < 8; ++j) {
                const float f = bf2f((unsigned short)h[j]);
                s = fmaf(f, f, s);
            }
        }
        red[r][q] = s;
    }
    __syncthreads();
    if (tid < 64)
        rowbias[tid] = -0.5f * (red[tid][0] + red[tid][1] + red[tid][2] +
                                red[tid][3] + epsn[row0 + tid]);
    __syncthreads();
    {   // U row norms
        const bf16x8* pu = (const bf16x8*)&Wb[(size_t)(1024 + col0 + r) * Dn + q * 64];
        float s = 0.f;
#pragma unroll
        for (int i = 0; i < 8; ++i) {
            const bf16x8 h = pu[i];
#pragma unroll
            for (int j = 0; j < 8; ++j) {
                const float f = bf2f((unsigned short)h[j]);
                s = fmaf(f, f, s);
            }
        }
        red[r][q] = s;
    }
    __syncthreads();
    if (tid < 64) {
        const int c = col0 + tid;
        colbias[tid] = (c < Cn)
            ? logits[c] - *lse_p - 0.5f * (red[tid][0] + red[tid][1] + red[tid][2] +
                                           red[tid][3] + epsn[1024 + c])
            : 0.f;
    }
    __syncthreads();

    const int lane = tid & 63, w = tid >> 6;
    const int wr = (w >> 1) * 32, wc = (w & 1) * 32;
    const int la = lane & 15, kg = lane >> 4;

    const bf16x8* pa = (const bf16x8*)&Wb[(size_t)(row0 + wr + la) * Dn + kg * 8];
    const bf16x8* pb = (const bf16x8*)&Wb[(size_t)(1024 + col0 + wc + la) * Dn + kg * 8];

    f32x4 acc00 = {0.f, 0.f, 0.f, 0.f};
    f32x4 acc01 = {0.f, 0.f, 0.f, 0.f};
    f32x4 acc10 = {0.f, 0.f, 0.f, 0.f};
    f32x4 acc11 = {0.f, 0.f, 0.f, 0.f};

#pragma unroll
    for (int kt = 0; kt < 8; ++kt) {
        const bf16x8 a0 = pa[kt * 4];
        const bf16x8 a1 = pa[kt * 4 + 512];
        const bf16x8 b0 = pb[kt * 4];
        const bf16x8 b1 = pb[kt * 4 + 512];
        acc00 = __builtin_amdgcn_mfma_f32_16x16x32_bf16(a0, b0, acc00, 0, 0, 0);
        acc01 = __builtin_amdgcn_mfma_f32_16x16x32_bf16(a0, b1, acc01, 0, 0, 0);
        acc10 = __builtin_amdgcn_mfma_f32_16x16x32_bf16(a1, b0, acc10, 0, 0, 0);
        acc11 = __builtin_amdgcn_mfma_f32_16x16x32_bf16(a1, b1, acc11, 0, 0, 0);
    }

    // C/D layout: col = lane&15, row = kg*4 + j
    const int rbase = kg * 4;
#define EPI(ACC, RF, CF)                                                        \
    do {                                                                        \
        const int gcl = wc + (CF)*16 + la;                                      \
        const int gc  = col0 + gcl;                                             \
        if (gc < Cn) {                                                          \
            const float cb = colbias[gcl];                                      \
            _Pragma("unroll")                                                   \
            for (int j = 0; j < 4; ++j) {                                       \
                const int rlc = wr + (RF)*16 + rbase + j;                       \
                out[(size_t)(row0 + rlc) * Cn + gc] = ACC[j] + rowbias[rlc] + cb; \
            }                                                                   \
        }                                                                       \
    } while (0)

    EPI(acc00, 0, 0); EPI(acc01, 0, 1); EPI(acc10, 1, 0); EPI(acc11, 1, 1);
#undef EPI
}

// ---------------------------------------------------------------------------
extern "C" void kernel_launch(void* const* d_in, const int* in_sizes, int n_in,
                              void* d_out, int out_size, void* d_ws, size_t ws_size,
                              hipStream_t stream) {
    const float* z      = (const float*)d_in[0];   // [1024][256]
    const float* mu     = (const float*)d_in[1];   // [1000][256]
    const float* logits = (const float*)d_in[2];   // [1000]
    const float* F      = (const float*)d_in[3];   // [256][256]
    float* out = (float*)d_out;                    // [1024][1000]

    char* ws = (char*)d_ws;
    unsigned short* Wb  = (unsigned short*)(ws);                   // 1 MB
    unsigned short* Gb  = (unsigned short*)(ws + (1 << 20));       // 1 MB
    unsigned short* Ftb = (unsigned short*)(ws + (2 << 20));       // 128 KB
    float* epsn = (float*)(ws + (2 << 20) + (128 << 10));          // 8 KB
    float* lse  = epsn + 2048;                                     // 4 B

    void* args[] = { (void*)&z, (void*)&mu, (void*)&logits, (void*)&F,
                     (void*)&Gb, (void*)&Ftb, (void*)&Wb,
                     (void*)&epsn, (void*)&lse, (void*)&out };
    hipLaunchCooperativeKernel((const void*)lda_fused_kernel,
                               dim3(256), dim3(256), args, 0, stream);
}

// Round 6
// 21.408 us; speedup vs baseline: 4.0419x; 4.0419x over previous
//
#include <hip/hip_runtime.h>
#include <hip/hip_bf16.h>
#include <math.h>

constexpr int Bn = 1024;   // batch
constexpr int Cn = 1000;   // classes
constexpr int Dn = 256;    // feature dim
constexpr float EPS = 1e-4f;

typedef __attribute__((ext_vector_type(8))) short bf16x8;
typedef __attribute__((ext_vector_type(4))) float f32x4;

// f32 -> bf16 round-to-nearest-even
static __device__ __forceinline__ unsigned short f2bf(float x) {
    union { float f; unsigned u; } v; v.f = x;
    return (unsigned short)((v.u + 0x7fffu + ((v.u >> 16) & 1u)) >> 16);
}
static __device__ __forceinline__ float bf2f(unsigned short h) {
    union { unsigned u; float f; } v; v.u = ((unsigned)h) << 16; return v.f;
}
static __device__ __forceinline__ bf16x8 cvt8(const float4 lo, const float4 hi) {
    bf16x8 r;
    r[0] = (short)f2bf(lo.x); r[1] = (short)f2bf(lo.y);
    r[2] = (short)f2bf(lo.z); r[3] = (short)f2bf(lo.w);
    r[4] = (short)f2bf(hi.x); r[5] = (short)f2bf(hi.y);
    r[6] = (short)f2bf(hi.z); r[7] = (short)f2bf(hi.w);
    return r;
}

// ---------------------------------------------------------------------------
// K1: Wb = bf16(G @ F), G = [z ; mu_clamped]  (rows 0..1023 = z, 1024.. = mu)
// 64 rows x 32 cols per block; MFMA with in-register f32->bf16 conversion.
// A-frags: per-lane row loads (2x float4). B-frags: F[k][n] per-j dword loads
// (coalesced across the 16 fragment lanes). No LDS.
// col0==0 blocks also write epsn = EPS*||row||^2; block 256 computes lse.
__global__ __launch_bounds__(256) void w_kernel(const float* __restrict__ z,
                                                const float* __restrict__ mu,
                                                const float* __restrict__ logits,
                                                const float* __restrict__ F,
                                                unsigned short* __restrict__ Wb,  // [2048][256]
                                                float* __restrict__ epsn,         // [2048]
                                                float* __restrict__ lse_p) {
    const int bid = blockIdx.x, tid = threadIdx.x;

    if (bid == 256) {   // lse = logsumexp(logits)
        __shared__ float rl[256];
        float mx = -INFINITY;
        for (int i = tid; i < Cn; i += 256) mx = fmaxf(mx, logits[i]);
        rl[tid] = mx; __syncthreads();
        for (int s = 128; s > 0; s >>= 1) {
            if (tid < s) rl[tid] = fmaxf(rl[tid], rl[tid + s]);
            __syncthreads();
        }
        mx = rl[0]; __syncthreads();
        float sm = 0.f;
        for (int i = tid; i < Cn; i += 256) sm += expf(logits[i] - mx);
        rl[tid] = sm; __syncthreads();
        for (int s = 128; s > 0; s >>= 1) {
            if (tid < s) rl[tid] += rl[tid + s];
            __syncthreads();
        }
        if (tid == 0) *lse_p = mx + logf(rl[0]);
        return;
    }

    const int row0 = (bid >> 3) * 64;   // 32 row tiles over G's 2048 rows
    const int col0 = (bid & 7) * 32;    // 8 col tiles
    const int lane = tid & 63, w = tid >> 6;
    const int wr = (w >> 1) * 32, wc = (w & 1) * 16;
    const int la = lane & 15, kg = lane >> 4;

    // per-lane A row pointers (f32 source)
    const int g0 = row0 + wr + la;
    const int g1 = g0 + 16;
    const float* arow0 = (g0 < 1024) ? &z[(size_t)g0 * Dn]
                                     : &mu[(size_t)min(g0 - 1024, Cn - 1) * Dn];
    const float* arow1 = (g1 < 1024) ? &z[(size_t)g1 * Dn]
                                     : &mu[(size_t)min(g1 - 1024, Cn - 1) * Dn];
    const int bcol = col0 + wc + la;

    f32x4 acc0 = {0.f, 0.f, 0.f, 0.f};
    f32x4 acc1 = {0.f, 0.f, 0.f, 0.f};

#pragma unroll
    for (int kt = 0; kt < 8; ++kt) {
        const int k0 = kt * 32 + kg * 8;
        const float4 a0lo = *(const float4*)&arow0[k0];
        const float4 a0hi = *(const float4*)&arow0[k0 + 4];
        const float4 a1lo = *(const float4*)&arow1[k0];
        const float4 a1hi = *(const float4*)&arow1[k0 + 4];
        bf16x8 b0;
#pragma unroll
        for (int j = 0; j < 8; ++j)
            b0[j] = (short)f2bf(F[(size_t)(k0 + j) * Dn + bcol]);
        const bf16x8 a0 = cvt8(a0lo, a0hi);
        const bf16x8 a1 = cvt8(a1lo, a1hi);
        acc0 = __builtin_amdgcn_mfma_f32_16x16x32_bf16(a0, b0, acc0, 0, 0, 0);
        acc1 = __builtin_amdgcn_mfma_f32_16x16x32_bf16(a1, b0, acc1, 0, 0, 0);
    }

    // C/D: col = lane&15, row = kg*4 + j
    const int rb0 = row0 + wr + kg * 4;
#pragma unroll
    for (int j = 0; j < 4; ++j) {
        Wb[(size_t)(rb0 + j) * Dn + bcol]      = f2bf(acc0[j]);
        Wb[(size_t)(rb0 + 16 + j) * Dn + bcol] = f2bf(acc1[j]);
    }

    if (col0 == 0) {   // epsn = EPS * ||G_row||^2 from f32 inputs
        __shared__ float red[64][4];
        const int r = tid >> 2, q = tid & 3;
        const int g = row0 + r;
        const float* src = (g < 1024) ? &z[(size_t)g * Dn]
                                      : &mu[(size_t)min(g - 1024, Cn - 1) * Dn];
        const float4* p4 = (const float4*)&src[q << 6];
        float s = 0.f;
#pragma unroll
        for (int i = 0; i < 16; ++i) {
            const float4 v = p4[i];
            s += v.x * v.x + v.y * v.y + v.z * v.z + v.w * v.w;
        }
        red[r][q] = s;
        __syncthreads();
        if (tid < 64)
            epsn[row0 + tid] = EPS * (red[tid][0] + red[tid][1] +
                                      red[tid][2] + red[tid][3]);
    }
}

// ---------------------------------------------------------------------------
// K2: out[b][c] = W_Y(b).W_U(c) + rowbias[b] + colbias[c]   (MFMA 64x64 tiles)
// rowbias = -0.5*(||Y_b||^2 + epsn_z), colbias = logit - lse - 0.5*(||U_c||^2 + epsn_mu)
// Norms recomputed in-block from bf16 Wb (L2-resident).
__global__ __launch_bounds__(256) void main_kernel(const unsigned short* __restrict__ Wb,
                                                   const float* __restrict__ epsn,
                                                   const float* __restrict__ logits,
                                                   const float* __restrict__ lse_p,
                                                   float* __restrict__ out) {
    __shared__ float red[64][4];
    __shared__ float rowbias[64], colbias[64];
    const int bid = blockIdx.x, tid = threadIdx.x;
    const int row0 = (bid >> 4) * 64;     // B rows
    const int col0 = (bid & 15) * 64;     // C cols
    const int r = tid >> 2, q = tid & 3;

    {   // Y row norms
        const bf16x8* py = (const bf16x8*)&Wb[(size_t)(row0 + r) * Dn + (q << 6)];
        float s = 0.f;
#pragma unroll
        for (int i = 0; i < 8; ++i) {
            const bf16x8 h = py[i];
#pragma unroll
            for (int j = 0; j < 8; ++j) {
                const float f = bf2f((unsigned short)h[j]);
                s = fmaf(f, f, s);
            }
        }
        red[r][q] = s;
    }
    __syncthreads();
    if (tid < 64)
        rowbias[tid] = -0.5f * (red[tid][0] + red[tid][1] + red[tid][2] +
                                red[tid][3] + epsn[row0 + tid]);
    __syncthreads();
    {   // U row norms
        const bf16x8* pu = (const bf16x8*)&Wb[(size_t)(1024 + col0 + r) * Dn + (q << 6)];
        float s = 0.f;
#pragma unroll
        for (int i = 0; i < 8; ++i) {
            const bf16x8 h = pu[i];
#pragma unroll
            for (int j = 0; j < 8; ++j) {
                const float f = bf2f((unsigned short)h[j]);
                s = fmaf(f, f, s);
            }
        }
        red[r][q] = s;
    }
    __syncthreads();
    if (tid < 64) {
        const int c = col0 + tid;
        colbias[tid] = (c < Cn)
            ? logits[c] - *lse_p - 0.5f * (red[tid][0] + red[tid][1] + red[tid][2] +
                                           red[tid][3] + epsn[1024 + c])
            : 0.f;
    }
    __syncthreads();

    const int lane = tid & 63, w = tid >> 6;
    const int wr = (w >> 1) * 32, wc = (w & 1) * 32;
    const int la = lane & 15, kg = lane >> 4;

    const bf16x8* pa = (const bf16x8*)&Wb[(size_t)(row0 + wr + la) * Dn + kg * 8];
    const bf16x8* pb = (const bf16x8*)&Wb[(size_t)(1024 + col0 + wc + la) * Dn + kg * 8];

    f32x4 acc00 = {0.f, 0.f, 0.f, 0.f};
    f32x4 acc01 = {0.f, 0.f, 0.f, 0.f};
    f32x4 acc10 = {0.f, 0.f, 0.f, 0.f};
    f32x4 acc11 = {0.f, 0.f, 0.f, 0.f};

#pragma unroll
    for (int kt = 0; kt < 8; ++kt) {
        const bf16x8 a0 = pa[kt * 4];
        const bf16x8 a1 = pa[kt * 4 + 512];
        const bf16x8 b0 = pb[kt * 4];
        const bf16x8 b1 = pb[kt * 4 + 512];
        acc00 = __builtin_amdgcn_mfma_f32_16x16x32_bf16(a0, b0, acc00, 0, 0, 0);
        acc01 = __builtin_amdgcn_mfma_f32_16x16x32_bf16(a0, b1, acc01, 0, 0, 0);
        acc10 = __builtin_amdgcn_mfma_f32_16x16x32_bf16(a1, b0, acc10, 0, 0, 0);
        acc11 = __builtin_amdgcn_mfma_f32_16x16x32_bf16(a1, b1, acc11, 0, 0, 0);
    }

    const int rbase = kg * 4;
#define EPI(ACC, RF, CF)                                                        \
    do {                                                                        \
        const int gcl = wc + (CF)*16 + la;                                      \
        const int gc  = col0 + gcl;                                             \
        if (gc < Cn) {                                                          \
            const float cb = colbias[gcl];                                      \
            _Pragma("unroll")                                                   \
            for (int j = 0; j < 4; ++j) {                                       \
                const int rlc = wr + (RF)*16 + rbase + j;                       \
                out[(size_t)(row0 + rlc) * Cn + gc] = ACC[j] + rowbias[rlc] + cb; \
            }                                                                   \
        }                                                                       \
    } while (0)

    EPI(acc00, 0, 0); EPI(acc01, 0, 1); EPI(acc10, 1, 0); EPI(acc11, 1, 1);
#undef EPI
}

// ---------------------------------------------------------------------------
extern "C" void kernel_launch(void* const* d_in, const int* in_sizes, int n_in,
                              void* d_out, int out_size, void* d_ws, size_t ws_size,
                              hipStream_t stream) {
    const float* z      = (const float*)d_in[0];   // [1024][256]
    const float* mu     = (const float*)d_in[1];   // [1000][256]
    const float* logits = (const float*)d_in[2];   // [1000]
    const float* F      = (const float*)d_in[3];   // [256][256]
    float* out = (float*)d_out;                    // [1024][1000]

    char* ws = (char*)d_ws;
    unsigned short* Wb = (unsigned short*)(ws);            // 1 MB [2048][256] bf16
    float* epsn = (float*)(ws + (1 << 20));                // 8 KB [2048]
    float* lse  = epsn + 2048;                             // 4 B

    w_kernel<<<dim3(257), dim3(256), 0, stream>>>(z, mu, logits, F, Wb, epsn, lse);
    main_kernel<<<dim3(256), dim3(256), 0, stream>>>(Wb, epsn, logits, lse, out);
}